// Round 5
// baseline (588.003 us; speedup 1.0000x reference)
//
#include <hip/hip_runtime.h>
#include <math.h>

#define N_NODES 100000
#define C_CH    64
#define E_EDGES 1200000
#define KD      32
#define HID     256
#define NPG     32
#define NGROUPS (N_NODES / NPG)          // 3125 exact
#define SBLK    ((N_NODES + 255) / 256)  // 391 scan blocks

typedef unsigned short ushort_t;
typedef short bf16x8 __attribute__((ext_vector_type(8)));
typedef float f32x4  __attribute__((ext_vector_type(4)));

__device__ __forceinline__ short f2bf(float f) {
    unsigned u = __builtin_bit_cast(unsigned, f);
    u = (u + 0x7fffu + ((u >> 16) & 1u)) >> 16;   // RNE
    return (short)u;
}
__device__ __forceinline__ float bf2f(ushort_t u) {
    return __builtin_bit_cast(float, (unsigned)u << 16);
}

// ---------------------------------------------------------------------------
// CSR build: hist -> two-level scan -> fill
// ---------------------------------------------------------------------------
__global__ __launch_bounds__(256) void hist_kernel(const int* __restrict__ ei,
                                                   int* __restrict__ deg) {
    int i = blockIdx.x * 256 + threadIdx.x;
    int stride = gridDim.x * 256;
    for (int e = i; e < E_EDGES; e += stride) {
        int dst = ei[E_EDGES + e];
        if ((unsigned)dst < (unsigned)N_NODES) atomicAdd(&deg[dst], 1);
    }
}

// per-block inclusive scan of 256 degrees -> block-local exclusive in off,
// block total in bsum
__global__ __launch_bounds__(256) void scan1_kernel(const int* __restrict__ deg,
                                                    int* __restrict__ off,
                                                    int* __restrict__ bsum) {
    __shared__ int s[256];
    const int t = threadIdx.x;
    const int i = blockIdx.x * 256 + t;
    int v = (i < N_NODES) ? deg[i] : 0;
    s[t] = v;
    __syncthreads();
    #pragma unroll
    for (int d = 1; d < 256; d <<= 1) {
        int u = (t >= d) ? s[t - d] : 0;
        __syncthreads();
        s[t] += u;
        __syncthreads();
    }
    if (i < N_NODES) off[i] = s[t] - v;          // exclusive within block
    if (t == 255) bsum[blockIdx.x] = s[255];
}

// single block: exclusive scan of 391 block sums; also writes off[N] = total
__global__ __launch_bounds__(512) void scan2_kernel(const int* __restrict__ bsum,
                                                    int* __restrict__ bpre,
                                                    int* __restrict__ off) {
    __shared__ int s[512];
    const int t = threadIdx.x;
    int v = (t < SBLK) ? bsum[t] : 0;
    s[t] = v;
    __syncthreads();
    #pragma unroll
    for (int d = 1; d < 512; d <<= 1) {
        int u = (t >= d) ? s[t - d] : 0;
        __syncthreads();
        s[t] += u;
        __syncthreads();
    }
    if (t < SBLK) bpre[t] = s[t] - v;
    if (t == 511) off[N_NODES] = s[511];
}

// add block prefix; initialize fill cursor pos = off
__global__ __launch_bounds__(256) void scan3_kernel(int* __restrict__ off,
                                                    const int* __restrict__ bpre,
                                                    int* __restrict__ pos) {
    const int i = blockIdx.x * 256 + threadIdx.x;
    if (i < N_NODES) {
        int val = off[i] + bpre[blockIdx.x];
        off[i] = val;
        pos[i] = val;
    }
}

__global__ __launch_bounds__(256) void fill_kernel(const int* __restrict__ ei,
                                                   int* __restrict__ pos,
                                                   int* __restrict__ eids) {
    int i = blockIdx.x * 256 + threadIdx.x;
    int stride = gridDim.x * 256;
    for (int e = i; e < E_EDGES; e += stride) {
        int dst = ei[E_EDGES + e];
        if ((unsigned)dst < (unsigned)N_NODES) {
            int p = atomicAdd(&pos[dst], 1);
            eids[p] = e;
        }
    }
}

// ---------------------------------------------------------------------------
// Gather: one wave per dst node, zero atomics.
// Per 16-edge tile: per-lane kb-row gather -> 4x MFMA -> fp32 coef in
// per-wave LDS (stride 68 dwords, <=2-way banks) -> 16 coalesced x-row
// loads (src broadcast via readlane) -> fp32 register accumulate.
// x1 written once per node (bf16).
// ---------------------------------------------------------------------------
__global__ __launch_bounds__(256) void gather_kernel(
    const float* __restrict__ x,  const float* __restrict__ kb,
    const int*   __restrict__ ei, const float* __restrict__ kW,
    const int*   __restrict__ off, const int* __restrict__ eids,
    ushort_t*    __restrict__ x1b)
{
    __shared__ float cbuf[4][16 * 68];   // per-wave coef tile, 17.4 KB

    const int t    = threadIdx.x;
    const int lane = t & 63;
    const int w    = __builtin_amdgcn_readfirstlane(t >> 6);
    const int nlo  = lane & 15;
    const int quad = lane >> 4;

    // B fragments: B[k][n] = kW[16tt+n][k], lane k = quad*8+j
    bf16x8 bW[4];
    #pragma unroll
    for (int tt = 0; tt < 4; ++tt) {
        const float* p = kW + (size_t)(16 * tt + nlo) * KD + quad * 8;
        #pragma unroll
        for (int q = 0; q < 8; ++q) bW[tt][q] = f2bf(p[q]);
    }

    float* srow = &cbuf[w][0];

    const int wid = blockIdx.x * 4 + (t >> 6);
    const int nw  = gridDim.x * 4;

    for (int n0 = wid; n0 < N_NODES; n0 += nw) {
        const int n   = __builtin_amdgcn_readfirstlane(n0);
        const int beg = off[n];
        const int end = off[n + 1];
        float acc = 0.f;

        for (int i = beg; i < end; i += 16) {
            // per-lane edge row (clamped to valid range; dup rows harmless)
            int ii = i + nlo;
            ii = (ii < end) ? ii : (end - 1);
            const int eidv = eids[ii];                 // per-lane gather
            const int srcv = ei[eidv];                 // per-lane gather

            // A fragment: kb[eidv][quad*8 .. +8]
            const float* ap = kb + (size_t)eidv * KD + quad * 8;
            float4 a0 = *(const float4*)ap;
            float4 a1 = *(const float4*)(ap + 4);
            bf16x8 af;
            af[0] = f2bf(a0.x); af[1] = f2bf(a0.y);
            af[2] = f2bf(a0.z); af[3] = f2bf(a0.w);
            af[4] = f2bf(a1.x); af[5] = f2bf(a1.y);
            af[6] = f2bf(a1.z); af[7] = f2bf(a1.w);

            #pragma unroll
            for (int tt = 0; tt < 4; ++tt) {
                f32x4 d = {0.f, 0.f, 0.f, 0.f};
                d = __builtin_amdgcn_mfma_f32_16x16x32_bf16(af, bW[tt], d, 0, 0, 0);
                #pragma unroll
                for (int r = 0; r < 4; ++r)
                    srow[(quad * 4 + r) * 68 + tt * 16 + nlo] = d[r];
            }
            // per-wave buffer: within-wave lgkmcnt ordering only, no barrier

            const int r16 = end - i;                   // uniform
            #pragma unroll
            for (int j = 0; j < 16; ++j) {
                if (j >= r16) break;                   // uniform branch
                const int src = __builtin_amdgcn_readlane(srcv, j);
                const float cf = srow[j * 68 + lane];
                acc += x[(size_t)src * C_CH + lane] * cf;
            }
        }
        x1b[(size_t)n * C_CH + lane] = (ushort_t)f2bf(acc);
    }
}

// ---------------------------------------------------------------------------
// Node: conv_bias + LN (fp32) -> bf16 MFMA GEMM1 -> exact GELU -> bf16 MFMA
// GEMM2 -> layerscale + residual. grid 512 (weights preloaded once per block,
// ~6 groups amortized); 3 barriers per group.
// ---------------------------------------------------------------------------
__global__ __launch_bounds__(256, 2) void node_kernel(
    const float* __restrict__ x,  const ushort_t* __restrict__ x1b,
    const float* __restrict__ conv_bias, const float* __restrict__ gamma,
    const float* __restrict__ beta, const float* __restrict__ W1,
    const float* __restrict__ b1, const float* __restrict__ W2,
    const float* __restrict__ b2, const float* __restrict__ ls,
    float* __restrict__ out)
{
    __shared__ short lnb[NPG][C_CH + 8];
    __shared__ short gb[NPG][HID + 8];

    const int t    = threadIdx.x;
    const int lane = t & 63;
    const int w    = t >> 6;
    const int nlo  = lane & 15;
    const int quad = lane >> 4;

    bf16x8 b1f[4][2];
    float  b1v[4];
    #pragma unroll
    for (int t1 = 0; t1 < 4; ++t1) {
        const int j = (4 * w + t1) * 16 + nlo;
        b1v[t1] = b1[j];
        #pragma unroll
        for (int s = 0; s < 2; ++s) {
            const float* p = W1 + (size_t)j * C_CH + s * 32 + quad * 8;
            #pragma unroll
            for (int q = 0; q < 8; ++q) b1f[t1][s][q] = f2bf(p[q]);
        }
    }
    bf16x8 b2f[8];
    #pragma unroll
    for (int s2 = 0; s2 < 8; ++s2) {
        const float* p = W2 + (size_t)(w * 16 + nlo) * HID + s2 * 32 + quad * 8;
        #pragma unroll
        for (int q = 0; q < 8; ++q) b2f[s2][q] = f2bf(p[q]);
    }
    const float biasc  = conv_bias[lane];
    const float gammac = gamma[lane];
    const float betac  = beta[lane];
    const float b2v    = b2[w * 16 + nlo];
    const float lsv    = ls[w * 16 + nlo];

    for (int g = blockIdx.x; g < NGROUPS; g += gridDim.x) {
        const int base = g * NPG;

        #pragma unroll
        for (int q = 0; q < 8; ++q) {
            const int loc = w * 8 + q;
            float v = bf2f(x1b[(size_t)(base + loc) * C_CH + lane]) + biasc;
            float s = v, ss = v * v;
            #pragma unroll
            for (int o = 32; o > 0; o >>= 1) {
                s  += __shfl_xor(s,  o, 64);
                ss += __shfl_xor(ss, o, 64);
            }
            float mu   = s * (1.f / 64.f);
            float rstd = rsqrtf(ss * (1.f / 64.f) - mu * mu + 1e-5f);
            lnb[loc][lane] = f2bf((v - mu) * rstd * gammac + betac);
        }
        __syncthreads();

        #pragma unroll
        for (int mt = 0; mt < 2; ++mt) {
            bf16x8 a1[2];
            #pragma unroll
            for (int s = 0; s < 2; ++s)
                a1[s] = *(const bf16x8*)&lnb[mt * 16 + nlo][s * 32 + quad * 8];
            #pragma unroll
            for (int t1 = 0; t1 < 4; ++t1) {
                f32x4 c = {0.f, 0.f, 0.f, 0.f};
                c = __builtin_amdgcn_mfma_f32_16x16x32_bf16(a1[0], b1f[t1][0], c, 0, 0, 0);
                c = __builtin_amdgcn_mfma_f32_16x16x32_bf16(a1[1], b1f[t1][1], c, 0, 0, 0);
                #pragma unroll
                for (int r = 0; r < 4; ++r) {
                    float h = c[r] + b1v[t1];
                    h = 0.5f * h * (1.f + erff(h * 0.70710678f));
                    gb[mt * 16 + quad * 4 + r][(4 * w + t1) * 16 + nlo] = f2bf(h);
                }
            }
        }
        __syncthreads();

        #pragma unroll
        for (int mt = 0; mt < 2; ++mt) {
            f32x4 c2 = {0.f, 0.f, 0.f, 0.f};
            #pragma unroll
            for (int s2 = 0; s2 < 8; ++s2) {
                bf16x8 a2 = *(const bf16x8*)&gb[mt * 16 + nlo][s2 * 32 + quad * 8];
                c2 = __builtin_amdgcn_mfma_f32_16x16x32_bf16(a2, b2f[s2], c2, 0, 0, 0);
            }
            #pragma unroll
            for (int r = 0; r < 4; ++r) {
                const int node = base + mt * 16 + quad * 4 + r;
                const int cch  = w * 16 + nlo;
                float h2 = c2[r] + b2v;
                out[(size_t)node * C_CH + cch] =
                    lsv * h2 + x[(size_t)node * C_CH + cch];
            }
        }
        __syncthreads();   // protect gb: next group's phase-2 writes
    }
}

extern "C" void kernel_launch(void* const* d_in, const int* in_sizes, int n_in,
                              void* d_out, int out_size, void* d_ws, size_t ws_size,
                              hipStream_t stream) {
    const float* x   = (const float*)d_in[0];
    const float* kb  = (const float*)d_in[1];
    // d_in[2] = fiber_kernel_basis (unused)
    const int*   ei  = (const int*)d_in[3];
    const float* kW  = (const float*)d_in[4];
    const float* cb  = (const float*)d_in[5];
    const float* gm  = (const float*)d_in[6];
    const float* bt  = (const float*)d_in[7];
    const float* W1  = (const float*)d_in[8];
    const float* b1  = (const float*)d_in[9];
    const float* W2  = (const float*)d_in[10];
    const float* b2  = (const float*)d_in[11];
    const float* ls  = (const float*)d_in[12];
    float* out = (float*)d_out;

    // workspace layout
    char* ws = (char*)d_ws;
    ushort_t* x1b  = (ushort_t*)ws;                   // 12,800,000 B
    int*      off  = (int*)(ws + 12800000);           // (N+1)*4 -> pad to 400,064
    int*      pos  = (int*)(ws + 13200064);           // 400,000 B (deg, then cursor)
    int*      bsum = (int*)(ws + 13600064);           // 391*4 -> pad 1,600
    int*      bpre = (int*)(ws + 13601664);           // 391*4 -> pad 1,600
    int*      eids = (int*)(ws + 13603264);           // (E+64)*4 B

    hipMemsetAsync(pos, 0, N_NODES * sizeof(int), stream);
    hist_kernel <<<1024, 256, 0, stream>>>(ei, pos);
    scan1_kernel<<<SBLK, 256, 0, stream>>>(pos, off, bsum);
    scan2_kernel<<<1,    512, 0, stream>>>(bsum, bpre, off);
    scan3_kernel<<<SBLK, 256, 0, stream>>>(off, bpre, pos);
    fill_kernel <<<1024, 256, 0, stream>>>(ei, pos, eids);
    gather_kernel<<<4096, 256, 0, stream>>>(x, kb, ei, kW, off, eids, x1b);
    node_kernel <<<512,  256, 0, stream>>>(x, x1b, cb, gm, bt, W1, b1, W2, b2, ls, out);
}